// Round 16
// baseline (174052.429 us; speedup 1.0000x reference)
//
#include <hip/hip_runtime.h>

#define HID   1024
#define SEQT  8192
#define NBLK  256
#define TPB   640   // 10 waves: 0-3 L1 compute, 4-7 L2 compute, 8 h1-poll, 9 h2-poll

// ws (bytes): [0,16K) u64 h1t[2][1024] ; [16K,32K) u64 h2t[2][1024]
// packed slot: (tag<<32)|fp32_bits ; h(s) in slot s&1 with tag s+1; init 0
#define WS_BYTES 32768

typedef float v16f __attribute__((ext_vector_type(16)));
typedef unsigned long long u64;

__device__ __forceinline__ float sig_(float x) { return 1.0f / (1.0f + expf(-x)); }

__device__ __forceinline__ u64 ldp(const u64* p) {
    return __hip_atomic_load(p, __ATOMIC_RELAXED, __HIP_MEMORY_SCOPE_AGENT);
}
__device__ __forceinline__ void stp(u64* p, u64 v) {
    __hip_atomic_store(p, v, __ATOMIC_RELAXED, __HIP_MEMORY_SCOPE_AGENT);
}

extern "C" __global__ void __launch_bounds__(TPB, 1)
lstm_pc(const float* __restrict__ seq,
        const float* __restrict__ w_ih1, const float* __restrict__ w_hh1,
        const float* __restrict__ b_ih1, const float* __restrict__ b_hh1,
        const float* __restrict__ w_ih2, const float* __restrict__ w_hh2,
        const float* __restrict__ b_ih2, const float* __restrict__ b_hh2,
        const float* __restrict__ w_lin, const float* __restrict__ b_lin,
        float* __restrict__ out, u64* ws)
{
    __shared__ float h1s[2][HID];   // staged h1, dbuf by t&1    8 KB
    __shared__ float h2s[2][HID];   // staged h2, dbuf by t&1    8 KB
    __shared__ float seqs[SEQT];    // input sequence           32 KB

    const int  lane = threadIdx.x & 63;
    const int  widx = threadIdx.x >> 6;        // 0..9
    const int  blk  = blockIdx.x;
    const bool isCompute = (widx < 8);
    const bool isL1 = (widx < 4);
    const int  r    = blk * 4 + (widx & 3);    // owned hidden row (compute waves)

    u64* h1t = ws;            // [2][1024]
    u64* h2t = ws + 2048;     // [2][1024]

    for (int i = threadIdx.x; i < SEQT; i += TPB) seqs[i] = seq[i];

    // ---- stationary weights (champion config: branch-free select; compiler
    // streams from L1/L2, fully overlapped with the sync chain) ----
    const float* bA  = isL1 ? w_hh1 : w_ih2;
    const float* bB  = isL1 ? w_hh1 : w_hh2;   // L1: B-dot zeroed via zmask
    const float* bbi = isL1 ? b_ih1 : b_ih2;
    const float* bbh = isL1 ? b_hh1 : b_hh2;
    const float  zmask = isL1 ? 0.f : 1.f;
    const float  xsel  = isL1 ? 1.f : 0.f;

    v16f A0, A1, A2, A3, B0, B1, B2, B3;
    float wx0 = 0.f, wx1 = 0.f, wx2 = 0.f, wx3 = 0.f;
    float bb0 = 0.f, bb1 = 0.f, bb2 = 0.f, bb3 = 0.f;
    if (isCompute) {
        const size_t ro = (size_t)r * HID + lane;
        const float *a0 = bA + ro, *a1 = bA + (size_t)HID * HID + ro,
                    *a2 = bA + 2 * (size_t)HID * HID + ro, *a3 = bA + 3 * (size_t)HID * HID + ro;
        const float *b0 = bB + ro, *b1 = bB + (size_t)HID * HID + ro,
                    *b2 = bB + 2 * (size_t)HID * HID + ro, *b3 = bB + 3 * (size_t)HID * HID + ro;
#pragma unroll
        for (int k = 0; k < 16; ++k) {
            A0[k] = a0[64 * k]; A1[k] = a1[64 * k]; A2[k] = a2[64 * k]; A3[k] = a3[64 * k];
            B0[k] = b0[64 * k]; B1[k] = b1[64 * k]; B2[k] = b2[64 * k]; B3[k] = b3[64 * k];
        }
        wx0 = w_ih1[0 * HID + r]; wx1 = w_ih1[1 * HID + r];
        wx2 = w_ih1[2 * HID + r]; wx3 = w_ih1[3 * HID + r];
        bb0 = bbi[0 * HID + r] + bbh[0 * HID + r];
        bb1 = bbi[1 * HID + r] + bbh[1 * HID + r];
        bb2 = bbi[2 * HID + r] + bbh[2 * HID + r];
        bb3 = bbi[3 * HID + r] + bbh[3 * HID + r];
    }

    const bool carrier = (blk == 0 && widx == 7);   // an L2 compute wave
    v16f WL; float blin = 0.f;
#pragma unroll
    for (int k = 0; k < 16; ++k) WL[k] = 0.f;
    if (carrier) {
#pragma unroll
        for (int k = 0; k < 16; ++k) WL[k] = w_lin[lane + 64 * k];
        blin = b_lin[0];
    }

    u64* pub = isL1 ? h1t : h2t;
    float c = 0.f;

    // Producer/consumer schedule, ONE barrier per step:
    //   iteration t: pollers stage step-t inputs into buf[t&1]; barrier;
    //   compute waves run step t (L1 -> h1(t), L2 -> h2(t-1), OUT -> out(t-2))
    //   while pollers loop ahead and poll step t+1 into buf[(t+1)&1].
    // Detect(t+1) thus overlaps compute(t): period = max(compute+publish,
    // visibility+detect) instead of their sum.
    // Overwrite safety (global slots): publish at t follows barrier(t), which
    // follows this block's pollers staging step-t data; h1(t-1) full implies
    // every block passed barrier(t-1), i.e. finished reading h1(t-2)/h2(t-3)
    // -> no readers of the slots clobbered at step t. LDS dbuf safety: buffer
    // t&1 is re-staged at t+2 only after barrier(t+1) = compute(t) done.
    for (int t = 0; t <= SEQT + 1; ++t) {
        const int cur = t & 1;

        if (widx == 8 && t <= SEQT) {
            // poll h1(t-1): slot (t+1)&1, tag >= t (t=0: init tag 0 passes)
            const u64* p = h1t + ((t + 1) & 1) * HID + lane;
            int guard = 0;
            for (;;) {
                int mn = 0x7fffffff;
                u64 q[16];
#pragma unroll
                for (int k = 0; k < 16; ++k) {
                    q[k] = ldp(p + 64 * k);
                    mn = min(mn, (int)(q[k] >> 32));
                }
#pragma unroll
                for (int k = 0; k < 16; ++k)
                    h1s[cur][lane + 64 * k] = __uint_as_float((unsigned)q[k]);
                if (__all(mn >= t)) break;
                if (++guard > (1 << 14)) break;   // bounded: fail loud, fast
            }
        }
        if (widx == 9) {
            // poll h2(t-2): slot t&1, tag >= t-1 (t<=1: init tag 0 passes)
            const u64* p = h2t + cur * HID + lane;
            const int thr = t - 1;
            int guard = 0;
            for (;;) {
                int mn = 0x7fffffff;
                u64 q[16];
#pragma unroll
                for (int k = 0; k < 16; ++k) {
                    q[k] = ldp(p + 64 * k);
                    mn = min(mn, (int)(q[k] >> 32));
                }
#pragma unroll
                for (int k = 0; k < 16; ++k)
                    h2s[cur][lane + 64 * k] = __uint_as_float((unsigned)q[k]);
                if (__all(mn >= thr)) break;
                if (++guard > (1 << 14)) break;
            }
        }
        __syncthreads();   // step-t inputs staged; compute(t-1) finished

        if (isCompute) {
            const bool act = isL1 ? (t < SEQT) : (t >= 1 && t <= SEQT);
            if (act) {
                v16f v1, v2;
#pragma unroll
                for (int k = 0; k < 16; ++k) {
                    v1[k] = h1s[cur][lane + 64 * k];
                    v2[k] = h2s[cur][lane + 64 * k] * zmask;
                }
                float a0 = 0.f, a1 = 0.f, a2 = 0.f, a3 = 0.f;
#pragma unroll
                for (int k = 0; k < 16; ++k) {
                    a0 = fmaf(A0[k], v1[k], a0);
                    a1 = fmaf(A1[k], v1[k], a1);
                    a2 = fmaf(A2[k], v1[k], a2);
                    a3 = fmaf(A3[k], v1[k], a3);
                }
#pragma unroll
                for (int k = 0; k < 16; ++k) {
                    a0 = fmaf(B0[k], v2[k], a0);
                    a1 = fmaf(B1[k], v2[k], a1);
                    a2 = fmaf(B2[k], v2[k], a2);
                    a3 = fmaf(B3[k], v2[k], a3);
                }
#pragma unroll
                for (int s = 32; s; s >>= 1) {
                    a0 += __shfl_xor(a0, s);
                    a1 += __shfl_xor(a1, s);
                    a2 += __shfl_xor(a2, s);
                    a3 += __shfl_xor(a3, s);
                }
                const float xg = xsel * ((t < SEQT) ? seqs[t] : 0.f);
                float i_ = sig_(a0 + xg * wx0 + bb0);
                float f_ = sig_(a1 + xg * wx1 + bb1);
                float g_ = tanhf(a2 + xg * wx2 + bb2);
                float o_ = sig_(a3 + xg * wx3 + bb3);
                c = f_ * c + i_ * g_;
                float h = o_ * tanhf(c);
                if (lane == 0) {
                    const int ps = isL1 ? t : (t - 1);   // produced timestep
                    stp(pub + (ps & 1) * HID + r,
                        ((u64)(unsigned)(ps + 1) << 32) | (u64)__float_as_uint(h));
                }
            }

            // out(t-2) from staged h2s[cur] (f32, exact)
            if (carrier && t >= 2) {
                float ov = 0.f;
#pragma unroll
                for (int k = 0; k < 16; ++k)
                    ov = fmaf(WL[k], h2s[cur][lane + 64 * k], ov);
#pragma unroll
                for (int s = 32; s; s >>= 1) ov += __shfl_xor(ov, s);
                if (lane == 0) out[t - 2] = ov + blin;
            }
        }
        // NO second barrier: pollers race ahead to t+1 (buf[(t+1)&1] was last
        // read by compute(t-1), which finished before this iteration's barrier)
    }
}

extern "C" void kernel_launch(void* const* d_in, const int* in_sizes, int n_in,
                              void* d_out, int out_size, void* d_ws, size_t ws_size,
                              hipStream_t stream)
{
    (void)hipMemsetAsync(d_ws, 0, WS_BYTES, stream);

    const float* seq  = (const float*)d_in[0];
    const float* wih1 = (const float*)d_in[1];
    const float* whh1 = (const float*)d_in[2];
    const float* bih1 = (const float*)d_in[3];
    const float* bhh1 = (const float*)d_in[4];
    const float* wih2 = (const float*)d_in[5];
    const float* whh2 = (const float*)d_in[6];
    const float* bih2 = (const float*)d_in[7];
    const float* bhh2 = (const float*)d_in[8];
    const float* wlin = (const float*)d_in[9];
    const float* blin = (const float*)d_in[10];
    float* out = (float*)d_out;
    u64*   ws  = (u64*)d_ws;

    hipLaunchKernelGGL(lstm_pc, dim3(NBLK), dim3(TPB), 0, stream,
                       seq, wih1, whh1, bih1, bhh1,
                       wih2, whh2, bih2, bhh2, wlin, blin,
                       out, ws);
}

// Round 17
// 25062.918 us; speedup vs baseline: 6.9446x; 6.9446x over previous
//
#include <hip/hip_runtime.h>

#define HID   1024
#define SEQT  8192
#define NBLK  256
#define TPB   512   // 8 waves: widx 0-3 = L1 rows, widx 4-7 = L2 rows

// ws layout: [0,32K) sync region: u64 h1t[2][1024] ; u64 h2t[2][1024]
//            [32K, 32K+24M) f16 weight copies: whh1 | wih2 | whh2
#define SYNC_BYTES 32768
#define WMAT_ELEMS (4u * 1024u * 1024u)          // one 4H x H matrix
#define W16_ELEMS  (3u * WMAT_ELEMS)             // 12,582,912
#define WS_NEED    ((size_t)SYNC_BYTES + (size_t)W16_ELEMS * 2)

typedef float v16f __attribute__((ext_vector_type(16)));
typedef unsigned long long u64;

__device__ __forceinline__ float sig_(float x) { return 1.0f / (1.0f + expf(-x)); }

__device__ __forceinline__ u64 ldp(const u64* p) {
    return __hip_atomic_load(p, __ATOMIC_RELAXED, __HIP_MEMORY_SCOPE_AGENT);
}
__device__ __forceinline__ void stp(u64* p, u64 v) {
    __hip_atomic_store(p, v, __ATOMIC_RELAXED, __HIP_MEMORY_SCOPE_AGENT);
}

#define PIN(v) asm volatile("" : "+v"(v))

// one-time per-launch converter: 3 gate matrices f32 -> f16 into ws
extern "C" __global__ void conv_w16(const float* __restrict__ whh1,
                                    const float* __restrict__ wih2,
                                    const float* __restrict__ whh2,
                                    _Float16* __restrict__ dst)
{
    for (unsigned i = blockIdx.x * blockDim.x + threadIdx.x; i < WMAT_ELEMS;
         i += gridDim.x * blockDim.x) {
        dst[i]                  = (_Float16)whh1[i];
        dst[i + WMAT_ELEMS]     = (_Float16)wih2[i];
        dst[i + 2 * WMAT_ELEMS] = (_Float16)whh2[i];
    }
}

// Round-9 champion skeleton, templated on streamed-weight element type.
template <class WT>
__global__ void __launch_bounds__(TPB, 2)
lstm_hyb_t(const float* __restrict__ seq,
           const float* __restrict__ w_ih1,
           const WT* __restrict__ wA1,      // L1 A-src: w_hh1
           const WT* __restrict__ wA2,      // L2 A-src: w_ih2
           const WT* __restrict__ wB2,      // L2 B-src: w_hh2
           const float* __restrict__ b_ih1, const float* __restrict__ b_hh1,
           const float* __restrict__ b_ih2, const float* __restrict__ b_hh2,
           const float* __restrict__ w_lin, const float* __restrict__ b_lin,
           float* __restrict__ out, u64* ws)
{
    __shared__ float h1s[HID];    // h1(t-1) values, staged by wave 0
    __shared__ float h2s[HID];    // h2(t-2) values, staged by wave 4
    __shared__ float seqs[SEQT];  // whole input sequence (32 KB)

    const int  lane = threadIdx.x & 63;
    const int  widx = threadIdx.x >> 6;        // 0..7
    const bool isL1 = (widx < 4);
    const int  r    = blockIdx.x * 4 + (widx & 3);   // owned hidden row

    u64* h1t = ws;            // [2][1024]
    u64* h2t = ws + 2048;     // [2][1024]

    for (int i = threadIdx.x; i < SEQT; i += TPB) seqs[i] = seq[i];

    // ---- stationary weights, BRANCH-FREE load + unconditional use ----
    const WT* bA = isL1 ? wA1 : wA2;
    const WT* bB = isL1 ? wA1 : wB2;           // L1: B-dot zeroed via zmask
    const float* bbi = isL1 ? b_ih1 : b_ih2;
    const float* bbh = isL1 ? b_hh1 : b_hh2;
    const float  zmask = isL1 ? 0.f : 1.f;
    const float  xsel  = isL1 ? 1.f : 0.f;

    v16f A0, A1, A2, A3, B0, B1, B2, B3;
    {
        const size_t ro = (size_t)r * HID + lane;
        const WT *a0 = bA + ro, *a1 = bA + (size_t)HID * HID + ro,
                 *a2 = bA + 2 * (size_t)HID * HID + ro, *a3 = bA + 3 * (size_t)HID * HID + ro;
        const WT *b0 = bB + ro, *b1 = bB + (size_t)HID * HID + ro,
                 *b2 = bB + 2 * (size_t)HID * HID + ro, *b3 = bB + 3 * (size_t)HID * HID + ro;
#pragma unroll
        for (int k = 0; k < 16; ++k) {
            A0[k] = (float)a0[64 * k]; A1[k] = (float)a1[64 * k];
            A2[k] = (float)a2[64 * k]; A3[k] = (float)a3[64 * k];
            B0[k] = (float)b0[64 * k]; B1[k] = (float)b1[64 * k];
            B2[k] = (float)b2[64 * k]; B3[k] = (float)b3[64 * k];
        }
    }
    PIN(A0); PIN(A1); PIN(A2); PIN(A3);
    PIN(B0); PIN(B1); PIN(B2); PIN(B3);

    const float wx0 = w_ih1[0 * HID + r], wx1 = w_ih1[1 * HID + r],
                wx2 = w_ih1[2 * HID + r], wx3 = w_ih1[3 * HID + r];
    const float bb0 = bbi[0 * HID + r] + bbh[0 * HID + r];
    const float bb1 = bbi[1 * HID + r] + bbh[1 * HID + r];
    const float bb2 = bbi[2 * HID + r] + bbh[2 * HID + r];
    const float bb3 = bbi[3 * HID + r] + bbh[3 * HID + r];

    const bool carrier = (blockIdx.x == 0 && widx == 7);   // an L2 wave
    v16f WL; float blin = 0.f;
#pragma unroll
    for (int k = 0; k < 16; ++k) WL[k] = 0.f;
    if (carrier) {
#pragma unroll
        for (int k = 0; k < 16; ++k) WL[k] = w_lin[lane + 64 * k];
        blin = b_lin[0];
    }

    u64* pub = isL1 ? h1t : h2t;
    float c = 0.f;

    // Lock-step schedule, one device-wide phase per t (t = 0 .. SEQT+1):
    //   L1  computes h1(t)    [t < SEQT]   from h1(t-1)           (h1s)
    //   L2  computes h2(t-1)  [1<=t<=SEQT] from h1(t-1), h2(t-2)  (h1s,h2s)
    //   OUT computes out(t-2) [t >= 2]     from h2(t-2)           (h2s)
    // Overwrite safety: publish(t) <= this block saw h2(t-2) full <= all
    // blocks' step-(t-1) polls completed -> no readers of clobbered slots.
    for (int t = 0; t <= SEQT + 1; ++t) {
        PIN(A0); PIN(A1); PIN(A2); PIN(A3);
        PIN(B0); PIN(B1); PIN(B2); PIN(B3);

        if (widx == 0 && t <= SEQT) {
            // poll h1(t-1): slot (t+1)&1, tag >= t (t=0: init tag 0 passes)
            const u64* p = h1t + ((t + 1) & 1) * HID + lane;
            int guard = 0;
            for (;;) {
                int mn = 0x7fffffff;
                u64 q[16];
#pragma unroll
                for (int k = 0; k < 16; ++k) {
                    q[k] = ldp(p + 64 * k);
                    mn = min(mn, (int)(q[k] >> 32));
                }
#pragma unroll
                for (int k = 0; k < 16; ++k)
                    h1s[lane + 64 * k] = __uint_as_float((unsigned)q[k]);
                if (__all(mn >= t)) break;
                if (++guard > (1 << 14)) break;   // bounded: fail loud, fast
            }
        }
        if (widx == 4) {
            // poll h2(t-2): slot t&1, tag >= t-1 (t<=1: init tag 0 passes)
            const u64* p = h2t + (t & 1) * HID + lane;
            const int thr = t - 1;
            int guard = 0;
            for (;;) {
                int mn = 0x7fffffff;
                u64 q[16];
#pragma unroll
                for (int k = 0; k < 16; ++k) {
                    q[k] = ldp(p + 64 * k);
                    mn = min(mn, (int)(q[k] >> 32));
                }
#pragma unroll
                for (int k = 0; k < 16; ++k)
                    h2s[lane + 64 * k] = __uint_as_float((unsigned)q[k]);
                if (__all(mn >= thr)) break;
                if (++guard > (1 << 14)) break;
            }
        }
        __syncthreads();

        const bool act = isL1 ? (t < SEQT) : (t >= 1 && t <= SEQT);
        if (act) {
            v16f v1, v2;
#pragma unroll
            for (int k = 0; k < 16; ++k) {
                v1[k] = h1s[lane + 64 * k];
                v2[k] = h2s[lane + 64 * k] * zmask;
            }
            float a0 = 0.f, a1 = 0.f, a2 = 0.f, a3 = 0.f;
#pragma unroll
            for (int k = 0; k < 16; ++k) {
                a0 = fmaf(A0[k], v1[k], a0);
                a1 = fmaf(A1[k], v1[k], a1);
                a2 = fmaf(A2[k], v1[k], a2);
                a3 = fmaf(A3[k], v1[k], a3);
            }
#pragma unroll
            for (int k = 0; k < 16; ++k) {
                a0 = fmaf(B0[k], v2[k], a0);
                a1 = fmaf(B1[k], v2[k], a1);
                a2 = fmaf(B2[k], v2[k], a2);
                a3 = fmaf(B3[k], v2[k], a3);
            }
#pragma unroll
            for (int s = 32; s; s >>= 1) {
                a0 += __shfl_xor(a0, s);
                a1 += __shfl_xor(a1, s);
                a2 += __shfl_xor(a2, s);
                a3 += __shfl_xor(a3, s);
            }
            const float xg = xsel * ((t < SEQT) ? seqs[t] : 0.f);
            float i_ = sig_(a0 + xg * wx0 + bb0);
            float f_ = sig_(a1 + xg * wx1 + bb1);
            float g_ = tanhf(a2 + xg * wx2 + bb2);
            float o_ = sig_(a3 + xg * wx3 + bb3);
            c = f_ * c + i_ * g_;
            float h = o_ * tanhf(c);
            if (lane == 0) {
                const int ps = isL1 ? t : (t - 1);   // produced timestep
                stp(pub + (ps & 1) * HID + r,
                    ((u64)(unsigned)(ps + 1) << 32) | (u64)__float_as_uint(h));
            }
        }

        // out(t-2) from staged h2s (f32, exact)
        if (carrier && t >= 2) {
            float ov = 0.f;
#pragma unroll
            for (int k = 0; k < 16; ++k) ov = fmaf(WL[k], h2s[lane + 64 * k], ov);
#pragma unroll
            for (int s = 32; s; s >>= 1) ov += __shfl_xor(ov, s);
            if (lane == 0) out[t - 2] = ov + blin;
        }

        __syncthreads();   // protect LDS from next step's restaging
    }
}

extern "C" void kernel_launch(void* const* d_in, const int* in_sizes, int n_in,
                              void* d_out, int out_size, void* d_ws, size_t ws_size,
                              hipStream_t stream)
{
    (void)hipMemsetAsync(d_ws, 0, SYNC_BYTES, stream);

    const float* seq  = (const float*)d_in[0];
    const float* wih1 = (const float*)d_in[1];
    const float* whh1 = (const float*)d_in[2];
    const float* bih1 = (const float*)d_in[3];
    const float* bhh1 = (const float*)d_in[4];
    const float* wih2 = (const float*)d_in[5];
    const float* whh2 = (const float*)d_in[6];
    const float* bih2 = (const float*)d_in[7];
    const float* bhh2 = (const float*)d_in[8];
    const float* wlin = (const float*)d_in[9];
    const float* blin = (const float*)d_in[10];
    float* out = (float*)d_out;
    u64*   ws  = (u64*)d_ws;

    if (ws_size >= WS_NEED) {
        _Float16* w16 = (_Float16*)((char*)d_ws + SYNC_BYTES);
        hipLaunchKernelGGL(conv_w16, dim3(2048), dim3(256), 0, stream,
                           whh1, wih2, whh2, w16);
        hipLaunchKernelGGL((lstm_hyb_t<_Float16>), dim3(NBLK), dim3(TPB), 0, stream,
                           seq, wih1,
                           (const _Float16*)w16,
                           (const _Float16*)(w16 + WMAT_ELEMS),
                           (const _Float16*)(w16 + 2 * WMAT_ELEMS),
                           bih1, bhh1, bih2, bhh2, wlin, blin, out, ws);
    } else {
        // fallback: exact round-9 champion (f32 streamed weights)
        hipLaunchKernelGGL((lstm_hyb_t<float>), dim3(NBLK), dim3(TPB), 0, stream,
                           seq, wih1, whh1, wih2, whh2,
                           bih1, bhh1, bih2, bhh2, wlin, blin, out, ws);
    }
}